// Round 4
// baseline (243.887 us; speedup 1.0000x reference)
//
#include <hip/hip_runtime.h>

typedef _Float16 f16;
typedef _Float16 f16x4 __attribute__((ext_vector_type(4)));
typedef _Float16 f16x8 __attribute__((ext_vector_type(8)));
typedef float f32x4 __attribute__((ext_vector_type(4)));
typedef int int4v __attribute__((ext_vector_type(4)));

constexpr int SP = 65536;  // 16^4

#define GLD16(g, l) __builtin_amdgcn_global_load_lds( \
  (const __attribute__((address_space(1))) void*)(g), \
  (__attribute__((address_space(3))) void*)(l), 16, 0, 0)

// ---------------------------------------------------------------------------
// Weight transform: fp32 [Cout][Cin][3^4] -> f16 [81][CoutP][Cin].
// Layer1 -> [32][96] (k = tap, zero-padded 81..95). Layer4 Cout 1 -> 16 pad.
// Half-element ws offsets: w1t 0 / w2t 3072 / w3t 168960 / w4t 334848 /
// a1 376320 / a2 4570624 (a3 aliases a1).
// ---------------------------------------------------------------------------
__global__ __launch_bounds__(256) void wtrans_k(
    const float* __restrict__ w1, const float* __restrict__ w2,
    const float* __restrict__ w3, const float* __restrict__ w4,
    f16* __restrict__ wt)
{
  int i = blockIdx.x * 256 + threadIdx.x;
  if (i < 3072) {
    int co = i / 96, k = i - co * 96;
    wt[i] = (k < 81) ? (f16)w1[co * 81 + k] : (f16)0.f;
  } else if (i < 168960) {
    int j = i - 3072;
    int t = j >> 11, r = j & 2047;
    int co = r >> 5, ci = r & 31;
    wt[i] = (f16)w2[(co * 32 + ci) * 81 + t];
  } else if (i < 334848) {
    int j = i - 168960;
    int t = j >> 11, r = j & 2047;
    int co = r >> 6, ci = r & 63;
    wt[i] = (f16)w3[(co * 64 + ci) * 81 + t];
  } else if (i < 376320) {
    int j = i - 334848;
    int t = j >> 9, r = j & 511;
    int co = r >> 5, ci = r & 31;
    wt[i] = (co == 0) ? (f16)w4[ci * 81 + t] : (f16)0.f;
  }
}

// XCD-aware swizzle for 512 blocks: XCD k (= raw%8) gets contiguous chunk of
// 64 (b,d1,d2) triples -> per-XCD input footprint fits 4 MB L2. (Verified:
// FETCH 132MB -> 12.6MB.)
__device__ inline int xcd_swizzle(int raw) { return (raw & 7) * 64 + (raw >> 3); }

// ---------------------------------------------------------------------------
// Layer 1: Cin=1, Cout=32, fp32 in -> f16 channels-last out.
// ---------------------------------------------------------------------------
__global__ __launch_bounds__(256) void conv_l1_k(
    const float* __restrict__ x, const f16* __restrict__ w1t,
    const float* __restrict__ bias, f16* __restrict__ aout)
{
  __shared__ float H1[9 * 324];
  __shared__ f16 Bexp[256 * 104];
  const int tid = threadIdx.x;
  const int bid = xcd_swizzle(blockIdx.x);
  const int b = bid >> 8;
  const int d1 = (bid >> 4) & 15, d2 = bid & 15;
  const float* xb = x + b * SP;

  for (int idx = tid; idx < 9 * 324; idx += 256) {
    int e = idx / 324, c = idx - e * 324;
    int h3 = c / 18, h4 = c - h3 * 18;
    int e1 = e / 3, e2 = e - e1 * 3;
    int dd1 = d1 + e1 - 1, dd2 = d2 + e2 - 1;
    int dd3 = h3 - 1, dd4 = h4 - 1;
    float v = 0.f;
    if (((unsigned)dd1 < 16u) & ((unsigned)dd2 < 16u) &
        ((unsigned)dd3 < 16u) & ((unsigned)dd4 < 16u))
      v = xb[((dd1 * 16 + dd2) * 16 + dd3) * 16 + dd4];
    H1[idx] = v;
  }
  __syncthreads();
  {
    int d3 = tid >> 4, d4 = tid & 15;
    f16* bp = Bexp + tid * 104;
    #pragma unroll
    for (int k = 0; k < 96; ++k) {
      float v = 0.f;
      if (k < 81) {
        int e = k / 9, rem = k - e * 9;
        int o3 = rem / 3, o4 = rem - o3 * 3;
        v = H1[e * 324 + (d3 + o3) * 18 + (d4 + o4)];
      }
      bp[k] = (f16)v;
    }
  }
  __syncthreads();

  const int lane = tid & 63, wave = tid >> 6;
  const int lm = lane & 15, kp = lane >> 4;
  f32x4 acc[2][4] = {};
  #pragma unroll
  for (int k0 = 0; k0 < 96; k0 += 32) {
    f16x8 a0 = *(const f16x8*)(w1t + lm * 96 + k0 + kp * 8);
    f16x8 a1 = *(const f16x8*)(w1t + (16 + lm) * 96 + k0 + kp * 8);
    #pragma unroll
    for (int nt = 0; nt < 4; ++nt) {
      int n = (wave * 4 + nt) * 16 + lm;
      f16x8 bf = *(const f16x8*)(Bexp + n * 104 + k0 + kp * 8);
      acc[0][nt] = __builtin_amdgcn_mfma_f32_16x16x32_f16(a0, bf, acc[0][nt], 0, 0, 0);
      acc[1][nt] = __builtin_amdgcn_mfma_f32_16x16x32_f16(a1, bf, acc[1][nt], 0, 0, 0);
    }
  }
  #pragma unroll
  for (int mt = 0; mt < 2; ++mt) {
    int co = mt * 16 + kp * 4;
    const float* bp = bias + co;
    #pragma unroll
    for (int nt = 0; nt < 4; ++nt) {
      int d3 = wave * 4 + nt;
      f16x4 pk;
      #pragma unroll
      for (int r = 0; r < 4; ++r)
        pk[r] = (f16)fmaxf(acc[mt][nt][r] + bp[r], 0.f);
      *(f16x4*)(aout + (bid * 256 + d3 * 16 + lm) * 32 + co) = pk;
    }
  }
}

// ---------------------------------------------------------------------------
// Layers 2..4: tap-decomposed implicit GEMM.
// Per stage s=(ck,e): 18x18 halo plane of 32-ci cells (64B) staged to LDS via
// global_load_lds with a bank-swizzle applied as SOURCE permutation (linear
// LDS dest, per G21): 16B-unit u holds quarter q'=((u&3)-c-(c>>2))&3 of cell
// c=u>>2; compute reads unit u = 4c + ((kp+c+(c>>2))&3) -> 2 lanes/bank.
// Schedule per stage: [A-group-0 regs | issue prefetch(s+1) | sched_barrier |
// 3 o3-groups: (prefetch A-group g+1) + inline B ds_reads + MFMAs |
// vmcnt(0)+lgkmcnt(0) | s_barrier]. One barrier per stage: the prefetch is
// issued AFTER the barrier all waves crossed post-compute(s-1), so the
// 2-buffer overwrite hazard is covered; counted A-waits never force the
// prefetch GLDs early (GLDs are older than only group-0 loads).
// ---------------------------------------------------------------------------
template<int CIN, int COUTP, bool RELU, bool FINAL>
__global__ __launch_bounds__(256, 2) void conv_layer_k(
    const f16* __restrict__ ain, const f16* __restrict__ wt,
    const float* __restrict__ bias, f16* __restrict__ aout,
    float* __restrict__ fout)
{
  constexpr int MT = COUTP / 16;
  constexpr int NCK = CIN / 32;
  constexpr int NSTAGE = NCK * 9;
  constexpr int BUFU = 1360;               // 16B units/buffer (covers unit 1355)
  __shared__ f16 hal[2 * BUFU * 8];        // 43,520 B -> 2 blocks/CU

  const int tid = threadIdx.x;
  const int bid = xcd_swizzle(blockIdx.x);
  const int b = bid >> 8;
  const int d1 = (bid >> 4) & 15, d2 = bid & 15;
  const int lane = tid & 63, wave = tid >> 6;
  const int lm = lane & 15, kp = lane >> 4;

  f32x4 acc[MT][4] = {};

  auto issue = [&](int s) {
    int ck = (NCK == 2) ? (s >= 9 ? 1 : 0) : 0;
    int e = s - ck * 9;
    int e1 = e / 3, e2 = e - e1 * 3;
    int dd1 = d1 + e1 - 1, dd2 = d2 + e2 - 1;
    bool pok = ((unsigned)dd1 < 16u) & ((unsigned)dd2 < 16u);
    const f16* pbase = ain + (size_t)(((b * 16 + dd1) * 16 + dd2) * 256) * CIN + ck * 32;
    f16* bufb = hal + (s & 1) * (BUFU * 8);
    #pragma unroll
    for (int j = 0; j < 6; ++j) {
      int g = wave * 324 + j * 64 + lane;      // 16B-unit index (linear dest)
      int cell = g >> 2;
      int srcq = ((g & 3) - cell - (cell >> 2)) & 3;   // inverse swizzle on src
      int h3 = cell / 18, h4 = cell - h3 * 18;
      int dd3 = h3 - 1, dd4 = h4 - 1;
      bool ok = pok & ((unsigned)dd3 < 16u) & ((unsigned)dd4 < 16u);
      if (ok) {
        GLD16(pbase + (dd3 * 16 + dd4) * CIN + srcq * 8,
              bufb + (wave * 324 + j * 64) * 8);       // wave-uniform base
      } else {
        *(int4v*)(bufb + (size_t)g * 8) = (int4v){0, 0, 0, 0};
      }
    }
  };

  issue(0);
  asm volatile("s_waitcnt vmcnt(0) lgkmcnt(0)" ::: "memory");
  __builtin_amdgcn_s_barrier();

  for (int s = 0; s < NSTAGE; ++s) {
    int ck = (NCK == 2) ? (s >= 9 ? 1 : 0) : 0;
    int e = s - ck * 9;
    const f16* bufb = hal + (s & 1) * (BUFU * 8);
    const f16* wbase = wt + (size_t)(e * 9) * COUTP * CIN + ck * 32 + kp * 8 + (size_t)lm * CIN;

    // group-0 A fragments (taps e*9 + 0..2), double-buffered across o3 groups
    f16x8 A[2][3 * MT];
    #pragma unroll
    for (int t = 0; t < 3; ++t)
      #pragma unroll
      for (int mt = 0; mt < MT; ++mt)
        A[0][t * MT + mt] = *(const f16x8*)(wbase + (size_t)(t * COUTP + mt * 16) * CIN);

    if (s + 1 < NSTAGE) issue(s + 1);
    __builtin_amdgcn_sched_barrier(0);

    #pragma unroll
    for (int o3 = 0; o3 < 3; ++o3) {
      if (o3 < 2) {                       // prefetch next group's A
        #pragma unroll
        for (int t = 0; t < 3; ++t)
          #pragma unroll
          for (int mt = 0; mt < MT; ++mt)
            A[(o3 + 1) & 1][t * MT + mt] =
              *(const f16x8*)(wbase + (size_t)(((o3 + 1) * 3 + t) * COUTP + mt * 16) * CIN);
      }
      #pragma unroll
      for (int o4 = 0; o4 < 3; ++o4) {
        #pragma unroll
        for (int nt = 0; nt < 4; ++nt) {
          int row = wave * 4 + nt + o3;
          int cell = row * 18 + lm + o4;
          int u = cell * 4 + ((kp + cell + (cell >> 2)) & 3);
          const f16x8 bf = *(const f16x8*)(bufb + u * 8);
          #pragma unroll
          for (int mt = 0; mt < MT; ++mt)
            acc[mt][nt] = __builtin_amdgcn_mfma_f32_16x16x32_f16(
                A[o3 & 1][o4 * MT + mt], bf, acc[mt][nt], 0, 0, 0);
        }
      }
    }
    asm volatile("s_waitcnt vmcnt(0) lgkmcnt(0)" ::: "memory");
    __builtin_amdgcn_sched_barrier(0);
    __builtin_amdgcn_s_barrier();
    __builtin_amdgcn_sched_barrier(0);
  }

  if (FINAL) {
    if (kp == 0) {
      float bv = bias[0];
      #pragma unroll
      for (int nt = 0; nt < 4; ++nt) {
        int d3 = wave * 4 + nt;
        fout[bid * 256 + d3 * 16 + lm] = acc[0][nt][0] + bv;
      }
    }
  } else {
    #pragma unroll
    for (int mt = 0; mt < MT; ++mt) {
      int co = mt * 16 + kp * 4;
      const float* bp = bias + co;
      #pragma unroll
      for (int nt = 0; nt < 4; ++nt) {
        int d3 = wave * 4 + nt;
        f16x4 pk;
        #pragma unroll
        for (int r = 0; r < 4; ++r) {
          float v = acc[mt][nt][r] + bp[r];
          if (RELU) v = fmaxf(v, 0.f);
          pk[r] = (f16)v;
        }
        *(f16x4*)(aout + (size_t)(bid * 256 + d3 * 16 + lm) * COUTP + co) = pk;
      }
    }
  }
}

extern "C" void kernel_launch(void* const* d_in, const int* in_sizes, int n_in,
                              void* d_out, int out_size, void* d_ws, size_t ws_size,
                              hipStream_t stream)
{
  (void)in_sizes; (void)n_in; (void)out_size; (void)ws_size;
  const float* x  = (const float*)d_in[0];
  const float* w1 = (const float*)d_in[1];
  const float* b1 = (const float*)d_in[2];
  const float* w2 = (const float*)d_in[3];
  const float* b2 = (const float*)d_in[4];
  const float* w3 = (const float*)d_in[5];
  const float* b3 = (const float*)d_in[6];
  const float* w4 = (const float*)d_in[7];
  const float* b4 = (const float*)d_in[8];

  f16* ws  = (f16*)d_ws;
  f16* w1t = ws;
  f16* w2t = ws + 3072;
  f16* w3t = ws + 168960;
  f16* w4t = ws + 334848;
  f16* a1  = ws + 376320;
  f16* a2  = a1 + (size_t)2 * SP * 32;
  f16* a3  = a1;                      // a1 dead after layer 2 reads it
  float* out = (float*)d_out;

  wtrans_k<<<1470, 256, 0, stream>>>(w1, w2, w3, w4, ws);
  conv_l1_k<<<512, 256, 0, stream>>>(x, w1t, b1, a1);
  conv_layer_k<32, 64, true,  false><<<512, 256, 0, stream>>>(a1, w2t, b2, a2, nullptr);
  conv_layer_k<64, 32, true,  false><<<512, 256, 0, stream>>>(a2, w3t, b3, a3, nullptr);
  conv_layer_k<32, 16, false, true ><<<512, 256, 0, stream>>>(a3, w4t, b4, nullptr, out);
}

// Round 6
// 237.932 us; speedup vs baseline: 1.0250x; 1.0250x over previous
//
#include <hip/hip_runtime.h>

typedef _Float16 f16;
typedef _Float16 f16x4 __attribute__((ext_vector_type(4)));
typedef _Float16 f16x8 __attribute__((ext_vector_type(8)));
typedef float f32x4 __attribute__((ext_vector_type(4)));

constexpr int SP = 65536;  // 16^4

#define GLD16(g, l) __builtin_amdgcn_global_load_lds( \
  (const __attribute__((address_space(1))) void*)(g), \
  (__attribute__((address_space(3))) void*)(l), 16, 0, 0)

// ---------------------------------------------------------------------------
// ws layout (half-element offsets):
//   w1t   [0, 3072)         32*96   (layer1: [co][tap-padded-96])
//   w2t   [3072, 168960)    81*64*32  [tap][co][ci]
//   w3t   [168960, 334848)  81*32*64
//   w4t   [334848, 376320)  81*16*32
//   zpage [376320, 376448)  128 halves of zeros (OOB GLD source)
//   a1    [376448, +2*SP*32)   channels-last f16
//   a2    a1 + 4194304, 2*SP*64
//   a3    aliases a1
// ---------------------------------------------------------------------------
__global__ __launch_bounds__(256) void wtrans_k(
    const float* __restrict__ w1, const float* __restrict__ w2,
    const float* __restrict__ w3, const float* __restrict__ w4,
    f16* __restrict__ wt)
{
  int i = blockIdx.x * 256 + threadIdx.x;
  if (i < 3072) {
    int co = i / 96, k = i - co * 96;
    wt[i] = (k < 81) ? (f16)w1[co * 81 + k] : (f16)0.f;
  } else if (i < 168960) {
    int j = i - 3072;
    int t = j >> 11, r = j & 2047;
    int co = r >> 5, ci = r & 31;
    wt[i] = (f16)w2[(co * 32 + ci) * 81 + t];
  } else if (i < 334848) {
    int j = i - 168960;
    int t = j >> 11, r = j & 2047;
    int co = r >> 6, ci = r & 63;
    wt[i] = (f16)w3[(co * 64 + ci) * 81 + t];
  } else if (i < 376320) {
    int j = i - 334848;
    int t = j >> 9, r = j & 511;
    int co = r >> 5, ci = r & 31;
    wt[i] = (co == 0) ? (f16)w4[ci * 81 + t] : (f16)0.f;
  } else if (i < 376448) {
    wt[i] = (f16)0.f;                 // zero page
  }
}

// 512-block XCD swizzle (layer 1): verified FETCH 132MB -> 12.6MB.
__device__ inline int xcd_swizzle512(int raw) { return (raw & 7) * 64 + (raw >> 3); }

// ---------------------------------------------------------------------------
// Layer 1: Cin=1, Cout=32, fp32 in -> f16 channels-last out. (4-wave block;
// small share of runtime, unchanged this round.)
// ---------------------------------------------------------------------------
__global__ __launch_bounds__(256) void conv_l1_k(
    const float* __restrict__ x, const f16* __restrict__ w1t,
    const float* __restrict__ bias, f16* __restrict__ aout)
{
  __shared__ float H1[9 * 324];
  __shared__ f16 Bexp[256 * 104];
  const int tid = threadIdx.x;
  const int bid = xcd_swizzle512(blockIdx.x);
  const int b = bid >> 8;
  const int d1 = (bid >> 4) & 15, d2 = bid & 15;
  const float* xb = x + b * SP;

  for (int idx = tid; idx < 9 * 324; idx += 256) {
    int e = idx / 324, c = idx - e * 324;
    int h3 = c / 18, h4 = c - h3 * 18;
    int e1 = e / 3, e2 = e - e1 * 3;
    int dd1 = d1 + e1 - 1, dd2 = d2 + e2 - 1;
    int dd3 = h3 - 1, dd4 = h4 - 1;
    float v = 0.f;
    if (((unsigned)dd1 < 16u) & ((unsigned)dd2 < 16u) &
        ((unsigned)dd3 < 16u) & ((unsigned)dd4 < 16u))
      v = xb[((dd1 * 16 + dd2) * 16 + dd3) * 16 + dd4];
    H1[idx] = v;
  }
  __syncthreads();
  {
    int d3 = tid >> 4, d4 = tid & 15;
    f16* bp = Bexp + tid * 104;
    #pragma unroll
    for (int k = 0; k < 96; ++k) {
      float v = 0.f;
      if (k < 81) {
        int e = k / 9, rem = k - e * 9;
        int o3 = rem / 3, o4 = rem - o3 * 3;
        v = H1[e * 324 + (d3 + o3) * 18 + (d4 + o4)];
      }
      bp[k] = (f16)v;
    }
  }
  __syncthreads();

  const int lane = tid & 63, wave = tid >> 6;
  const int lm = lane & 15, kp = lane >> 4;
  f32x4 acc[2][4] = {};
  #pragma unroll
  for (int k0 = 0; k0 < 96; k0 += 32) {
    f16x8 a0 = *(const f16x8*)(w1t + lm * 96 + k0 + kp * 8);
    f16x8 a1 = *(const f16x8*)(w1t + (16 + lm) * 96 + k0 + kp * 8);
    #pragma unroll
    for (int nt = 0; nt < 4; ++nt) {
      int n = (wave * 4 + nt) * 16 + lm;
      f16x8 bf = *(const f16x8*)(Bexp + n * 104 + k0 + kp * 8);
      acc[0][nt] = __builtin_amdgcn_mfma_f32_16x16x32_f16(a0, bf, acc[0][nt], 0, 0, 0);
      acc[1][nt] = __builtin_amdgcn_mfma_f32_16x16x32_f16(a1, bf, acc[1][nt], 0, 0, 0);
    }
  }
  #pragma unroll
  for (int mt = 0; mt < 2; ++mt) {
    int co = mt * 16 + kp * 4;
    const float* bp = bias + co;
    #pragma unroll
    for (int nt = 0; nt < 4; ++nt) {
      int d3 = wave * 4 + nt;
      f16x4 pk;
      #pragma unroll
      for (int r = 0; r < 4; ++r)
        pk[r] = (f16)fmaxf(acc[mt][nt][r] + bp[r], 0.f);
      *(f16x4*)(aout + (bid * 256 + d3 * 16 + lm) * 32 + co) = pk;
    }
  }
}

// ---------------------------------------------------------------------------
// Layers 2..4: 1-WAVE workgroups, zero barriers. Each block = one wave owns
// 4 d3-rows x 16 d4 x all Cout of one (b,d1,d2) plane. Grid 2048 -> 8
// independent waves/CU; latency hidden by TLP + one-stage GLD prefetch with
// counted vmcnt(7). Halo per stage: 6 rows x 18 cols x 64B cells, linear LDS
// (bank-balanced: verified conflict counter is layout-invariant), double
// buffered (2 x 7168 B). OOB lanes load from a zero page -> uniform 7 GLDs
// per stage, sound counted vmcnt on edge planes.
// Per stage: 3 o3-groups { 3*MT A-loads (L1/L2) ; 3 o4 x 4 nt ds_read_b128
// + MT MFMA }. 72 MFMA/stage at MT=2.
// ---------------------------------------------------------------------------
template<int CIN, int COUTP, bool RELU, bool FINAL>
__global__ __launch_bounds__(64, 2) void conv_rows_k(
    const f16* __restrict__ ain, const f16* __restrict__ wt,
    const float* __restrict__ bias, const f16* __restrict__ zpage,
    f16* __restrict__ aout, float* __restrict__ fout)
{
  constexpr int MT = COUTP / 16;
  constexpr int NCK = CIN / 32;
  constexpr int NSTAGE = NCK * 9;
  constexpr int BUFH = 448 * 8;          // halves per buffer: 448 16B-units
  __shared__ f16 hal[2 * BUFH];          // 14,336 B -> 8+ blocks/CU

  const int raw = blockIdx.x;
  const int swz = (raw & 7) * 256 + (raw >> 3);   // XCD k gets planes [64k,64k+64)
  const int plane = swz >> 2;            // (b,d1,d2)
  const int rg = swz & 3;
  const int b = plane >> 8;
  const int d1 = (plane >> 4) & 15, d2 = plane & 15;
  const int r0 = rg * 4;
  const int lane = threadIdx.x;
  const int lm = lane & 15, kp = lane >> 4;

  f32x4 acc[MT][4] = {};

  auto issue = [&](int s) {
    int ck = (NCK == 2 && s >= 9) ? 1 : 0;
    int e = s - ck * 9;
    int e1 = e / 3, e2 = e - e1 * 3;
    int dd1 = d1 + e1 - 1, dd2 = d2 + e2 - 1;
    bool pok = ((unsigned)dd1 < 16u) & ((unsigned)dd2 < 16u);
    const f16* pbase = ain + ((size_t)((b * 16 + dd1) * 16 + dd2) * 256) * CIN + ck * 32;
    f16* dst = hal + (s & 1) * BUFH;
    #pragma unroll
    for (int j = 0; j < 7; ++j) {
      int t = j * 64 + lane;             // 16B-unit slot (448 total, 432 real)
      int u = (t < 432) ? t : 431;
      int cell = u >> 2, q = u & 3;
      int h3 = cell / 18, h4 = cell - h3 * 18;   // h3 0..5
      int dd3 = r0 - 1 + h3, dd4 = h4 - 1;
      bool ok = pok & ((unsigned)dd3 < 16u) & ((unsigned)dd4 < 16u) & (t < 432);
      const f16* src = ok ? (pbase + (size_t)(dd3 * 16 + dd4) * CIN + q * 8) : zpage;
      GLD16(src, dst + j * 512);         // wave-uniform dest; lane slot implicit
    }
  };

  issue(0);
  for (int s = 0; s < NSTAGE; ++s) {
    if (s + 1 < NSTAGE) {
      issue(s + 1);
      // 7 newest = stage s+1's GLDs; everything older (stage-s GLDs, prior
      // A-loads) must drain. Keeps the prefetch in flight across the stage.
      asm volatile("s_waitcnt vmcnt(7)" ::: "memory");
    } else {
      asm volatile("s_waitcnt vmcnt(0)" ::: "memory");
    }
    __builtin_amdgcn_sched_barrier(0);

    int ck = (NCK == 2 && s >= 9) ? 1 : 0;
    int e = s - ck * 9;
    const f16* buf = hal + (s & 1) * BUFH;
    const f16* wb = wt + (size_t)(e * 9) * COUTP * CIN + ck * 32 + (size_t)lm * CIN + kp * 8;
    #pragma unroll
    for (int o3 = 0; o3 < 3; ++o3) {
      f16x8 A[3 * MT];
      #pragma unroll
      for (int t = 0; t < 3; ++t)
        #pragma unroll
        for (int mt = 0; mt < MT; ++mt)
          A[t * MT + mt] = *(const f16x8*)(wb + (size_t)((o3 * 3 + t) * COUTP + mt * 16) * CIN);
      #pragma unroll
      for (int o4 = 0; o4 < 3; ++o4) {
        #pragma unroll
        for (int nt = 0; nt < 4; ++nt) {
          int cell = (nt + o3) * 18 + lm + o4;
          const f16x8 bf = *(const f16x8*)(buf + cell * 32 + kp * 8);
          #pragma unroll
          for (int mt = 0; mt < MT; ++mt)
            acc[mt][nt] = __builtin_amdgcn_mfma_f32_16x16x32_f16(
                A[o4 * MT + mt], bf, acc[mt][nt], 0, 0, 0);
        }
      }
    }
  }

  if (FINAL) {
    if (kp == 0) {                       // co=0 lives in kp=0, reg 0
      float bv = bias[0];
      #pragma unroll
      for (int nt = 0; nt < 4; ++nt)
        fout[plane * 256 + (r0 + nt) * 16 + lm] = acc[0][nt][0] + bv;
    }
  } else {
    #pragma unroll
    for (int mt = 0; mt < MT; ++mt) {
      int co = mt * 16 + kp * 4;
      const float* bp = bias + co;
      #pragma unroll
      for (int nt = 0; nt < 4; ++nt) {
        f16x4 pk;
        #pragma unroll
        for (int r = 0; r < 4; ++r) {
          float v = acc[mt][nt][r] + bp[r];
          if (RELU) v = fmaxf(v, 0.f);
          pk[r] = (f16)v;
        }
        *(f16x4*)(aout + ((size_t)(plane * 256 + (r0 + nt) * 16 + lm)) * COUTP + co) = pk;
      }
    }
  }
}

extern "C" void kernel_launch(void* const* d_in, const int* in_sizes, int n_in,
                              void* d_out, int out_size, void* d_ws, size_t ws_size,
                              hipStream_t stream)
{
  (void)in_sizes; (void)n_in; (void)out_size; (void)ws_size;
  const float* x  = (const float*)d_in[0];
  const float* w1 = (const float*)d_in[1];
  const float* b1 = (const float*)d_in[2];
  const float* w2 = (const float*)d_in[3];
  const float* b2 = (const float*)d_in[4];
  const float* w3 = (const float*)d_in[5];
  const float* b3 = (const float*)d_in[6];
  const float* w4 = (const float*)d_in[7];
  const float* b4 = (const float*)d_in[8];

  f16* ws  = (f16*)d_ws;
  f16* w1t = ws;
  f16* w2t = ws + 3072;
  f16* w3t = ws + 168960;
  f16* w4t = ws + 334848;
  f16* zpg = ws + 376320;
  f16* a1  = ws + 376448;
  f16* a2  = a1 + (size_t)2 * SP * 32;
  f16* a3  = a1;                      // a1 dead after layer 2 reads it
  float* out = (float*)d_out;

  wtrans_k<<<1471, 256, 0, stream>>>(w1, w2, w3, w4, ws);
  conv_l1_k<<<512, 256, 0, stream>>>(x, w1t, b1, a1);
  conv_rows_k<32, 64, true,  false><<<2048, 64, 0, stream>>>(a1, w2t, b2, zpg, a2, nullptr);
  conv_rows_k<64, 32, true,  false><<<2048, 64, 0, stream>>>(a2, w3t, b3, zpg, a3, nullptr);
  conv_rows_k<32, 16, false, true ><<<2048, 64, 0, stream>>>(a3, w4t, b4, zpg, nullptr, out);
}